// Round 13
// baseline (288.638 us; speedup 1.0000x reference)
//
#include <hip/hip_runtime.h>
#include <hip/hip_bf16.h>

typedef __bf16 bf16x8 __attribute__((ext_vector_type(8)));
typedef __bf16 bf16x4 __attribute__((ext_vector_type(4)));
typedef float f32x4 __attribute__((ext_vector_type(4)));

#define EB 256    // edges per block (edgeconv)
#define NSCAN 1024

// ---- ws layout (dword offsets) ----
#define OFF_COUNTS 0          // N dwords
#define OFF_STARTS 100000     // N+1 dwords
#define OFF_VAL    200016     // 128 dwords (lookback totals)
#define OFF_STATE  200144     // 128 dwords (lookback flags)
#define OFF_CSR    200448     // int2[E] = 2E dwords
// wab (bf16[12288]: wA|wB|w2t) at OFF_CSR + 2E     [6144 dwords]
// AB region                     at OFF_CSR+2E+6144 [N*64 dwords]:
//   slot (int[E])  ALIASES the AB region (dead before ab_kernel writes A/B)
//   Abf (bf16[N*64]), Bbf (bf16[N*64]) written by ab_kernel AFTER scatter
#define WAB_DW 6144

__device__ __forceinline__ unsigned short f2bf(float v) {
    unsigned int u = __float_as_uint(v);
    return (unsigned short)((u + 0x7fffu + ((u >> 16) & 1u)) >> 16);
}

__device__ __forceinline__ bf16x8 pack8(float4 a, float4 b) {
    bf16x8 r;
    r[0] = (__bf16)a.x; r[1] = (__bf16)a.y; r[2] = (__bf16)a.z; r[3] = (__bf16)a.w;
    r[4] = (__bf16)b.x; r[5] = (__bf16)b.y; r[6] = (__bf16)b.z; r[7] = (__bf16)b.w;
    return r;
}

// blocks [0,48): weight prep (wA = W1a - W1b, wB = W1b, w2t = W2^T);
//   block 0 also zeroes the lookback flags.
// blocks [48,..): histogram; atomicAdd return value IS the edge's slot
__global__ void prep_hist_kernel(const float* __restrict__ W1,
                                 const float* __restrict__ W2,
                                 unsigned short* __restrict__ wab,
                                 int* __restrict__ state,
                                 const int* __restrict__ ei,
                                 int* __restrict__ counts,
                                 int* __restrict__ slot, int E) {
    int b = blockIdx.x;
    if (b < 48) {
        if (b == 0 && threadIdx.x < 128) state[threadIdx.x] = 0;
        int t = b * 256 + threadIdx.x;
        if (t < 4096) {
            int c = t >> 6, k = t & 63;
            wab[t] = f2bf(W1[k * 64 + c] - W1[(64 + k) * 64 + c]);
        } else if (t < 8192) {
            int i = t - 4096;
            int c = i >> 6, k = i & 63;
            wab[t] = f2bf(W1[(64 + k) * 64 + c]);
        } else if (t < 12288) {
            int i = t - 8192;
            int o = i >> 6, c = i & 63;
            wab[t] = f2bf(W2[c * 64 + o]);
        }
        return;
    }
    int t = (b - 48) * 256 + threadIdx.x;
    int i = t * 4;
    if (i + 3 < E) {
        int4 d = *(const int4*)(ei + E + i);
        int4 s;
        s.x = atomicAdd(&counts[d.x], 1);
        s.y = atomicAdd(&counts[d.y], 1);
        s.z = atomicAdd(&counts[d.z], 1);
        s.w = atomicAdd(&counts[d.w], 1);
        *(int4*)(slot + i) = s;
    } else {
        for (int j = 0; j < 4 && i + j < E; ++j)
            slot[i + j] = atomicAdd(&counts[ei[E + i + j]], 1);
    }
}

// single-dispatch scan over counts -> starts (decoupled lookback, nb<=128
// blocks all co-resident); zero-fills out rows for zero-degree nodes.
__global__ void scan_fused_kernel(const int* __restrict__ counts,
                                  int* __restrict__ val, int* __restrict__ state,
                                  int* __restrict__ starts, float* __restrict__ out,
                                  int N, int E, int nb) {
    int b = blockIdx.x, t = threadIdx.x;
    int lane = t & 63, w = t >> 6;
    int base = b * NSCAN + t * 4;
    int c[4];
    #pragma unroll
    for (int q = 0; q < 4; ++q)
        c[q] = (base + q < N) ? counts[base + q] : 0;
    int tot = c[0] + c[1] + c[2] + c[3];

    // block total
    int s = tot;
    #pragma unroll
    for (int off = 1; off < 64; off <<= 1) s += __shfl_xor(s, off);
    __shared__ int wsum[4];
    if (lane == 0) wsum[w] = s;
    __syncthreads();

    __shared__ int sPrefix;
    if (t == 0) {
        int blockTot = wsum[0] + wsum[1] + wsum[2] + wsum[3];
        val[b] = blockTot;
        __threadfence();
        atomicExch(&state[b], 1);
        int pre = 0;
        for (int i = 0; i < b; ++i) {
            while (atomicAdd(&state[i], 0) == 0) { }
            pre += atomicAdd(&val[i], 0);
        }
        sPrefix = pre;
        if (b == nb - 1) starts[N] = E;
    }

    // local exclusive scan
    int inc = tot;
    #pragma unroll
    for (int off = 1; off < 64; off <<= 1) {
        int n = __shfl_up(inc, off);
        if (lane >= off) inc += n;
    }
    int excl = inc - tot;
    __shared__ int wtot[4];
    if (lane == 63) wtot[w] = inc;
    __syncthreads();   // covers sPrefix and wtot

    int woff = 0;
    for (int i = 0; i < w; ++i) woff += wtot[i];
    int run = sPrefix + woff + excl;
    #pragma unroll
    for (int q = 0; q < 4; ++q) {
        if (base + q < N) {
            starts[base + q] = run;
            if (c[q] == 0) {   // ~never (E = 16N random), but must be exact
                f32x4 z = (f32x4){0.f, 0.f, 0.f, 0.f};
                float* op = out + (long)(base + q) * 64;
                #pragma unroll
                for (int r = 0; r < 16; ++r) *(f32x4*)(op + r * 4) = z;
            }
            run += c[q];
        }
    }
}

// atomic-free scatter using precomputed slots (4 edges/thread)
__global__ void scatter_kernel(const int* __restrict__ ei, const int* __restrict__ starts,
                               const int* __restrict__ slot, int2* __restrict__ csr, int E) {
    int t = blockIdx.x * blockDim.x + threadIdx.x;
    int i = t * 4;
    if (i + 3 < E) {
        int4 s4 = *(const int4*)(ei + i);
        int4 d4 = *(const int4*)(ei + E + i);
        int4 sl = *(const int4*)(slot + i);
        csr[starts[d4.x] + sl.x] = make_int2(s4.x, d4.x);
        csr[starts[d4.y] + sl.y] = make_int2(s4.y, d4.y);
        csr[starts[d4.z] + sl.z] = make_int2(s4.z, d4.z);
        csr[starts[d4.w] + sl.w] = make_int2(s4.w, d4.w);
    } else {
        for (int j = 0; j < 4 && i + j < E; ++j) {
            int sE = ei[i + j], dE = ei[E + i + j];
            csr[starts[dE] + slot[i + j]] = make_int2(sE, dE);
        }
    }
}

// A = x @ wA^T + b1, B = x @ wB^T   (per node; bf16 out, f32 accum)
__global__ __launch_bounds__(256, 4)
void ab_kernel(const float* __restrict__ x,
               const unsigned short* __restrict__ wab,
               const float* __restrict__ b1,
               unsigned short* __restrict__ Abf,
               unsigned short* __restrict__ Bbf, int N) {
    const int lane = threadIdx.x & 63;
    const int w    = threadIdx.x >> 6;
    const int ln   = lane & 15;
    const int rg   = lane >> 4;
    const int n    = blockIdx.x * 64 + w * 16 + ln;
    const int nc   = min(n, N - 1);

    const float* xr = x + (long)nc * 64;
    float4 f0 = *(const float4*)(xr + rg * 8),      f1 = *(const float4*)(xr + rg * 8 + 4);
    float4 f2 = *(const float4*)(xr + 32 + rg * 8), f3 = *(const float4*)(xr + 32 + rg * 8 + 4);
    bf16x8 xk[2];
    xk[0] = pack8(f0, f1);
    xk[1] = pack8(f2, f3);

    const bf16x8* wAv = (const bf16x8*)wab;            // 64 rows x 8 frags
    const bf16x8* wBv = (const bf16x8*)(wab + 4096);

    f32x4 accA[4], accB[4];
    #pragma unroll
    for (int ct = 0; ct < 4; ++ct) {
        accA[ct] = (f32x4){0.f, 0.f, 0.f, 0.f};
        accB[ct] = (f32x4){0.f, 0.f, 0.f, 0.f};
    }
    #pragma unroll
    for (int kt = 0; kt < 2; ++kt) {
        #pragma unroll
        for (int ct = 0; ct < 4; ++ct) {
            accA[ct] = __builtin_amdgcn_mfma_f32_16x16x32_bf16(
                wAv[(ct * 16 + ln) * 8 + kt * 4 + rg], xk[kt], accA[ct], 0, 0, 0);
            accB[ct] = __builtin_amdgcn_mfma_f32_16x16x32_bf16(
                wBv[(ct * 16 + ln) * 8 + kt * 4 + rg], xk[kt], accB[ct], 0, 0, 0);
        }
    }
    if (n < N) {
        #pragma unroll
        for (int ct = 0; ct < 4; ++ct) {
            const int c0 = ct * 16 + rg * 4;
            float4 bv = *(const float4*)(b1 + c0);
            bf16x4 av, bvv;
            av[0] = (__bf16)(accA[ct][0] + bv.x);
            av[1] = (__bf16)(accA[ct][1] + bv.y);
            av[2] = (__bf16)(accA[ct][2] + bv.z);
            av[3] = (__bf16)(accA[ct][3] + bv.w);
            bvv[0] = (__bf16)accB[ct][0];
            bvv[1] = (__bf16)accB[ct][1];
            bvv[2] = (__bf16)accB[ct][2];
            bvv[3] = (__bf16)accB[ct][3];
            *(bf16x4*)(Abf + (long)n * 64 + c0) = av;
            *(bf16x4*)(Bbf + (long)n * 64 + c0) = bvv;
        }
    }
}

__global__ __launch_bounds__(256)
void edgeconv_kernel(const unsigned short* __restrict__ Abf,
                     const unsigned short* __restrict__ Bbf,
                     const int2* __restrict__ csr,
                     const int* __restrict__ starts,
                     const float* __restrict__ b2,
                     const unsigned short* __restrict__ wab,
                     float* __restrict__ out,
                     int E) {
    // sB (32KB): h2 bf16 [256][64], rows 128B, XOR swizzle (e&7)<<4 on 16B chunks.
    // Every phase is wave-local (wave w owns rows [w*64, w*64+64)) -> NO barrier.
    __shared__ __align__(16) unsigned char sB[EB * 128];

    const int tid  = threadIdx.x;         // 0..255 (4 waves)
    const int lane = tid & 63;
    const int w    = tid >> 6;            // wave 0..3
    const int ln   = lane & 15;
    const int rg   = lane >> 4;           // 0..3
    const int p0   = blockIdx.x * EB;

    const bf16x8* w2v = (const bf16x8*)(wab + 8192);

    // ---------------- gather + add + relu: 4 edge-tiles per wave ----------------
    // h1(e) = relu(A[dst] + B[src]); wave w owns edges e = (w*4+eti)*16 + ln.
    bf16x8 fr[4][2];
    #pragma unroll
    for (int eti = 0; eti < 4; ++eti) {
        const int p = p0 + (w * 4 + eti) * 16 + ln;
        int2 sd = (p < E) ? csr[p] : make_int2(0, 0);
        const unsigned short* Ai = Abf + (long)sd.y * 64;
        const unsigned short* Bj = Bbf + (long)sd.x * 64;
        bf16x8 a0 = *(const bf16x8*)(Ai + rg * 8);
        bf16x8 a1 = *(const bf16x8*)(Ai + 32 + rg * 8);
        bf16x8 q0 = *(const bf16x8*)(Bj + rg * 8);
        bf16x8 q1 = *(const bf16x8*)(Bj + 32 + rg * 8);
        #pragma unroll
        for (int j = 0; j < 8; ++j) {
            fr[eti][0][j] = (__bf16)fmaxf((float)a0[j] + (float)q0[j], 0.f);
            fr[eti][1][j] = (__bf16)fmaxf((float)a1[j] + (float)q1[j], 0.f);
        }
    }

    // ---------------- GEMM2: H2^T = W2^T @ H1^T (4 tiles share each weight frag) ----------------
    f32x4 acc2[4][4];
    #pragma unroll
    for (int eti = 0; eti < 4; ++eti)
        #pragma unroll
        for (int ot = 0; ot < 4; ++ot)
            acc2[eti][ot] = (f32x4){0.f, 0.f, 0.f, 0.f};

    #pragma unroll
    for (int kt = 0; kt < 2; ++kt) {
        #pragma unroll
        for (int ot = 0; ot < 4; ++ot) {
            bf16x8 wf = w2v[(ot * 16 + ln) * 8 + kt * 4 + rg];
            #pragma unroll
            for (int eti = 0; eti < 4; ++eti)
                acc2[eti][ot] = __builtin_amdgcn_mfma_f32_16x16x32_bf16(
                    wf, fr[eti][kt], acc2[eti][ot], 0, 0, 0);
        }
    }

    // ---------------- epilogue: bias+relu -> bf16 h2 -> sB (wave-local rows) ----------------
    #pragma unroll
    for (int eti = 0; eti < 4; ++eti) {
        const int e = (w * 4 + eti) * 16 + ln;
        unsigned char* rowp = sB + e * 128;
        const unsigned int swz = (unsigned int)(e & 7) << 4;
        #pragma unroll
        for (int ot = 0; ot < 4; ++ot) {
            const int c0 = ot * 16 + rg * 4;
            float4 bv = *(const float4*)(b2 + c0);
            bf16x4 hv;
            hv[0] = (__bf16)fmaxf(acc2[eti][ot][0] + bv.x, 0.f);
            hv[1] = (__bf16)fmaxf(acc2[eti][ot][1] + bv.y, 0.f);
            hv[2] = (__bf16)fmaxf(acc2[eti][ot][2] + bv.z, 0.f);
            hv[3] = (__bf16)fmaxf(acc2[eti][ot][3] + bv.w, 0.f);
            *(bf16x4*)(rowp + (((unsigned)(c0 * 2)) ^ swz)) = hv;
        }
    }

    // no barrier: each wave reduces only its own 64-edge span

    // ---------------- wave-local segmented max over dst groups ----------------
    {
        const int wlo = p0 + w * 64;
        const int whi = min(wlo + 64, E);
        if (wlo < E) {
            const int dfirst = csr[wlo].y;
            const int dlast  = csr[whi - 1].y;
            const int c = lane;
            for (int d = dfirst; d <= dlast; ++d) {
                const int s0 = starts[d], s1 = starts[d + 1];
                const int lo = max(s0, wlo), hi = min(s1, whi);
                if (lo >= hi) continue;  // zero-edge node inside range
                unsigned int m0 = 0, m1 = 0;  // bf16 bits; relu>=0 so bit-max == fp-max
                int p = lo;
                for (; p + 1 < hi; p += 2) {
                    const int e0 = p - p0, e1 = e0 + 1;
                    unsigned int v0 = *(const unsigned short*)(sB + e0 * 128 +
                                        (((unsigned)(c * 2)) ^ ((unsigned)(e0 & 7) << 4)));
                    unsigned int v1 = *(const unsigned short*)(sB + e1 * 128 +
                                        (((unsigned)(c * 2)) ^ ((unsigned)(e1 & 7) << 4)));
                    m0 = max(m0, v0);
                    m1 = max(m1, v1);
                }
                if (p < hi) {
                    const int e0 = p - p0;
                    unsigned int v0 = *(const unsigned short*)(sB + e0 * 128 +
                                        (((unsigned)(c * 2)) ^ ((unsigned)(e0 & 7) << 4)));
                    m0 = max(m0, v0);
                }
                float m = __uint_as_float(max(m0, m1) << 16);
                if (s0 >= wlo && s1 <= whi)
                    out[(long)d * 64 + c] = m;                                   // sole owner
                else
                    atomicMax((int*)out + (long)d * 64 + c, __float_as_int(m));  // boundary
            }
        }
    }
}

extern "C" void kernel_launch(void* const* d_in, const int* in_sizes, int n_in,
                              void* d_out, int out_size, void* d_ws, size_t ws_size,
                              hipStream_t stream) {
    const float* x  = (const float*)d_in[0];
    const int*   ei = (const int*)d_in[1];
    const float* W1 = (const float*)d_in[2];
    const float* b1 = (const float*)d_in[3];
    const float* W2 = (const float*)d_in[4];
    const float* b2 = (const float*)d_in[5];
    float* out = (float*)d_out;

    const int E = in_sizes[1] / 2;
    const int N = in_sizes[0] / 64;

    int* wsI = (int*)d_ws;
    int* counts  = wsI + OFF_COUNTS;
    int* starts  = wsI + OFF_STARTS;
    int* val     = wsI + OFF_VAL;
    int* state   = wsI + OFF_STATE;
    int2* csr    = (int2*)(wsI + OFF_CSR);
    unsigned short* wab = (unsigned short*)(wsI + OFF_CSR + 2 * E);
    unsigned short* Abf = (unsigned short*)(wsI + OFF_CSR + 2 * E + WAB_DW);
    unsigned short* Bbf = Abf + (long)N * 64;
    int* slot = (int*)Abf;   // aliases AB region; dead before ab_kernel runs

    hipMemsetAsync(counts, 0, (size_t)N * sizeof(int), stream);

    // weights prep + lookback-flag zero + histogram (fused)
    const int nbH = (E / 4 + 255) / 256 + 1;
    prep_hist_kernel<<<48 + nbH, 256, 0, stream>>>(W1, W2, wab, state, ei, counts, slot, E);

    const int nb2 = (N + NSCAN - 1) / NSCAN;
    scan_fused_kernel<<<nb2, 256, 0, stream>>>(counts, val, state, starts, out, N, E, nb2);

    const int nbS = (E / 4 + 255) / 256 + 1;
    scatter_kernel<<<nbS, 256, 0, stream>>>(ei, starts, slot, csr, E);

    // now slot is dead -> ab_kernel may overwrite the region
    const int nbAB = (N + 63) / 64;
    ab_kernel<<<nbAB, 256, 0, stream>>>(x, wab, b1, Abf, Bbf, N);

    const int nb = (E + EB - 1) / EB;
    edgeconv_kernel<<<nb, 256, 0, stream>>>(Abf, Bbf, csr, starts, b2, wab, out, E);
}

// Round 14
// 256.206 us; speedup vs baseline: 1.1266x; 1.1266x over previous
//
#include <hip/hip_runtime.h>
#include <hip/hip_bf16.h>

typedef __bf16 bf16x8 __attribute__((ext_vector_type(8)));
typedef __bf16 bf16x4 __attribute__((ext_vector_type(4)));
typedef float f32x4 __attribute__((ext_vector_type(4)));

#define EB 256    // edges per block (edgeconv)
#define NSCAN 1024

// ---- ws layout (dword offsets) ----
#define OFF_COUNTS 0          // N dwords
#define OFF_STARTS 100000     // N+1 dwords
#define OFF_BSUM   200016     // ~128 dwords
#define OFF_CSR    200160     // int2[E] = 2E dwords
// wab (bf16[12288]: wA|wB|w2t) at OFF_CSR + 2E     [6144 dwords]
// AB region                     at OFF_CSR+2E+6144 [N*64 dwords]:
//   slot (int[E])  ALIASES the AB region (dead before ab_kernel writes A/B)
//   Abf (bf16[N*64]), Bbf (bf16[N*64]) written by ab_kernel AFTER scatter
#define WAB_DW 6144

__device__ __forceinline__ unsigned short f2bf(float v) {
    unsigned int u = __float_as_uint(v);
    return (unsigned short)((u + 0x7fffu + ((u >> 16) & 1u)) >> 16);
}

__device__ __forceinline__ bf16x8 pack8(float4 a, float4 b) {
    bf16x8 r;
    r[0] = (__bf16)a.x; r[1] = (__bf16)a.y; r[2] = (__bf16)a.z; r[3] = (__bf16)a.w;
    r[4] = (__bf16)b.x; r[5] = (__bf16)b.y; r[6] = (__bf16)b.z; r[7] = (__bf16)b.w;
    return r;
}

// blocks [0,48): weight prep (wA = W1a - W1b, wB = W1b, w2t = W2^T)
// blocks [48,..): histogram; atomicAdd return value IS the edge's slot
__global__ void prep_hist_kernel(const float* __restrict__ W1,
                                 const float* __restrict__ W2,
                                 unsigned short* __restrict__ wab,
                                 const int* __restrict__ ei,
                                 int* __restrict__ counts,
                                 int* __restrict__ slot, int E) {
    int b = blockIdx.x;
    if (b < 48) {
        int t = b * 256 + threadIdx.x;
        if (t < 4096) {
            int c = t >> 6, k = t & 63;
            wab[t] = f2bf(W1[k * 64 + c] - W1[(64 + k) * 64 + c]);
        } else if (t < 8192) {
            int i = t - 4096;
            int c = i >> 6, k = i & 63;
            wab[t] = f2bf(W1[(64 + k) * 64 + c]);
        } else if (t < 12288) {
            int i = t - 8192;
            int o = i >> 6, c = i & 63;
            wab[t] = f2bf(W2[c * 64 + o]);
        }
        return;
    }
    int t = (b - 48) * 256 + threadIdx.x;
    int i = t * 4;
    if (i + 3 < E) {
        int4 d = *(const int4*)(ei + E + i);
        int4 s;
        s.x = atomicAdd(&counts[d.x], 1);
        s.y = atomicAdd(&counts[d.y], 1);
        s.z = atomicAdd(&counts[d.z], 1);
        s.w = atomicAdd(&counts[d.w], 1);
        *(int4*)(slot + i) = s;
    } else {
        for (int j = 0; j < 4 && i + j < E; ++j)
            slot[i + j] = atomicAdd(&counts[ei[E + i + j]], 1);
    }
}

__global__ void scanA_kernel(const int* __restrict__ counts, int* __restrict__ bsum, int N) {
    int b = blockIdx.x, t = threadIdx.x;
    int base = b * NSCAN + t * 4;
    int s = 0;
    #pragma unroll
    for (int q = 0; q < 4; ++q)
        if (base + q < N) s += counts[base + q];
    #pragma unroll
    for (int off = 1; off < 64; off <<= 1) s += __shfl_xor(s, off);
    __shared__ int wsum[4];
    if ((t & 63) == 0) wsum[t >> 6] = s;
    __syncthreads();
    if (t == 0) bsum[b] = wsum[0] + wsum[1] + wsum[2] + wsum[3];
}

// single wave; nb <= 128
__global__ void scanB_kernel(int* __restrict__ bsum, int* __restrict__ starts, int nb, int N, int E) {
    int lane = threadIdx.x;
    int v0 = (lane < nb) ? bsum[lane] : 0;
    int v1 = (64 + lane < nb) ? bsum[64 + lane] : 0;
    int s = v0;
    #pragma unroll
    for (int off = 1; off < 64; off <<= 1) {
        int n = __shfl_up(s, off);
        if (lane >= off) s += n;
    }
    int total0 = __shfl(s, 63);
    int s1 = v1;
    #pragma unroll
    for (int off = 1; off < 64; off <<= 1) {
        int n = __shfl_up(s1, off);
        if (lane >= off) s1 += n;
    }
    if (lane < nb) bsum[lane] = s - v0;
    if (64 + lane < nb) bsum[64 + lane] = total0 + s1 - v1;
    if (lane == 0) starts[N] = E;
}

// writes starts[]; zero-fills out rows for zero-degree nodes (no global memset)
__global__ void scanC_kernel(const int* __restrict__ counts, const int* __restrict__ bsum,
                             int* __restrict__ starts, float* __restrict__ out, int N) {
    int b = blockIdx.x, t = threadIdx.x;
    int lane = t & 63, w = t >> 6;
    int base = b * NSCAN + t * 4;
    int c[4];
    #pragma unroll
    for (int q = 0; q < 4; ++q)
        c[q] = (base + q < N) ? counts[base + q] : 0;
    int tot = c[0] + c[1] + c[2] + c[3];
    int inc = tot;
    #pragma unroll
    for (int off = 1; off < 64; off <<= 1) {
        int n = __shfl_up(inc, off);
        if (lane >= off) inc += n;
    }
    int excl = inc - tot;
    __shared__ int wtot[4];
    if (lane == 63) wtot[w] = inc;
    __syncthreads();
    int woff = 0;
    for (int i = 0; i < w; ++i) woff += wtot[i];
    int run = bsum[b] + woff + excl;
    #pragma unroll
    for (int q = 0; q < 4; ++q) {
        if (base + q < N) {
            starts[base + q] = run;
            if (c[q] == 0) {   // ~never (E = 16N random), but must be exact
                f32x4 z = (f32x4){0.f, 0.f, 0.f, 0.f};
                float* op = out + (long)(base + q) * 64;
                #pragma unroll
                for (int r = 0; r < 16; ++r) *(f32x4*)(op + r * 4) = z;
            }
            run += c[q];
        }
    }
}

// atomic-free scatter using precomputed slots (4 edges/thread)
__global__ void scatter_kernel(const int* __restrict__ ei, const int* __restrict__ starts,
                               const int* __restrict__ slot, int2* __restrict__ csr, int E) {
    int t = blockIdx.x * blockDim.x + threadIdx.x;
    int i = t * 4;
    if (i + 3 < E) {
        int4 s4 = *(const int4*)(ei + i);
        int4 d4 = *(const int4*)(ei + E + i);
        int4 sl = *(const int4*)(slot + i);
        csr[starts[d4.x] + sl.x] = make_int2(s4.x, d4.x);
        csr[starts[d4.y] + sl.y] = make_int2(s4.y, d4.y);
        csr[starts[d4.z] + sl.z] = make_int2(s4.z, d4.z);
        csr[starts[d4.w] + sl.w] = make_int2(s4.w, d4.w);
    } else {
        for (int j = 0; j < 4 && i + j < E; ++j) {
            int sE = ei[i + j], dE = ei[E + i + j];
            csr[starts[dE] + slot[i + j]] = make_int2(sE, dE);
        }
    }
}

// A = x @ wA^T + b1, B = x @ wB^T   (per node; bf16 out, f32 accum)
__global__ __launch_bounds__(256, 4)
void ab_kernel(const float* __restrict__ x,
               const unsigned short* __restrict__ wab,
               const float* __restrict__ b1,
               unsigned short* __restrict__ Abf,
               unsigned short* __restrict__ Bbf, int N) {
    const int lane = threadIdx.x & 63;
    const int w    = threadIdx.x >> 6;
    const int ln   = lane & 15;
    const int rg   = lane >> 4;
    const int n    = blockIdx.x * 64 + w * 16 + ln;
    const int nc   = min(n, N - 1);

    const float* xr = x + (long)nc * 64;
    float4 f0 = *(const float4*)(xr + rg * 8),      f1 = *(const float4*)(xr + rg * 8 + 4);
    float4 f2 = *(const float4*)(xr + 32 + rg * 8), f3 = *(const float4*)(xr + 32 + rg * 8 + 4);
    bf16x8 xk[2];
    xk[0] = pack8(f0, f1);
    xk[1] = pack8(f2, f3);

    const bf16x8* wAv = (const bf16x8*)wab;            // 64 rows x 8 frags
    const bf16x8* wBv = (const bf16x8*)(wab + 4096);

    f32x4 accA[4], accB[4];
    #pragma unroll
    for (int ct = 0; ct < 4; ++ct) {
        accA[ct] = (f32x4){0.f, 0.f, 0.f, 0.f};
        accB[ct] = (f32x4){0.f, 0.f, 0.f, 0.f};
    }
    #pragma unroll
    for (int kt = 0; kt < 2; ++kt) {
        #pragma unroll
        for (int ct = 0; ct < 4; ++ct) {
            accA[ct] = __builtin_amdgcn_mfma_f32_16x16x32_bf16(
                wAv[(ct * 16 + ln) * 8 + kt * 4 + rg], xk[kt], accA[ct], 0, 0, 0);
            accB[ct] = __builtin_amdgcn_mfma_f32_16x16x32_bf16(
                wBv[(ct * 16 + ln) * 8 + kt * 4 + rg], xk[kt], accB[ct], 0, 0, 0);
        }
    }
    if (n < N) {
        #pragma unroll
        for (int ct = 0; ct < 4; ++ct) {
            const int c0 = ct * 16 + rg * 4;
            float4 bv = *(const float4*)(b1 + c0);
            bf16x4 av, bvv;
            av[0] = (__bf16)(accA[ct][0] + bv.x);
            av[1] = (__bf16)(accA[ct][1] + bv.y);
            av[2] = (__bf16)(accA[ct][2] + bv.z);
            av[3] = (__bf16)(accA[ct][3] + bv.w);
            bvv[0] = (__bf16)accB[ct][0];
            bvv[1] = (__bf16)accB[ct][1];
            bvv[2] = (__bf16)accB[ct][2];
            bvv[3] = (__bf16)accB[ct][3];
            *(bf16x4*)(Abf + (long)n * 64 + c0) = av;
            *(bf16x4*)(Bbf + (long)n * 64 + c0) = bvv;
        }
    }
}

__global__ __launch_bounds__(256)
void edgeconv_kernel(const unsigned short* __restrict__ Abf,
                     const unsigned short* __restrict__ Bbf,
                     const int2* __restrict__ csr,
                     const int* __restrict__ starts,
                     const float* __restrict__ b2,
                     const unsigned short* __restrict__ wab,
                     float* __restrict__ out,
                     int E) {
    // sB (32KB): h2 bf16 [256][64], rows 128B, XOR swizzle (e&7)<<4 on 16B chunks.
    __shared__ __align__(16) unsigned char sB[EB * 128];

    const int tid  = threadIdx.x;         // 0..255 (4 waves)
    const int lane = tid & 63;
    const int w    = tid >> 6;            // wave 0..3
    const int ln   = lane & 15;
    const int rg   = lane >> 4;           // 0..3
    const int p0   = blockIdx.x * EB;
    const int p1   = min(p0 + EB, E);

    const bf16x8* w2v = (const bf16x8*)(wab + 8192);

    // ---------------- phase 1: issue ALL gather loads (max MLP) ----------------
    // h1(e) = relu(A[dst] + B[src]); wave w owns edges e = (w*4+eti)*16 + ln.
    int2 sd[4];
    #pragma unroll
    for (int eti = 0; eti < 4; ++eti) {
        const int p = p0 + (w * 4 + eti) * 16 + ln;
        sd[eti] = (p < E) ? csr[p] : make_int2(0, 0);
    }
    bf16x8 a0[4], a1[4], q0[4], q1[4];
    #pragma unroll
    for (int eti = 0; eti < 4; ++eti) {
        const unsigned short* Bj = Bbf + (long)sd[eti].x * 64;
        q0[eti] = *(const bf16x8*)(Bj + rg * 8);
        q1[eti] = *(const bf16x8*)(Bj + 32 + rg * 8);
    }
    #pragma unroll
    for (int eti = 0; eti < 4; ++eti) {
        const unsigned short* Ai = Abf + (long)sd[eti].y * 64;
        a0[eti] = *(const bf16x8*)(Ai + rg * 8);
        a1[eti] = *(const bf16x8*)(Ai + 32 + rg * 8);
    }

    // ---------------- phase 2: add + relu -> h1 fragments ----------------
    bf16x8 fr[4][2];
    #pragma unroll
    for (int eti = 0; eti < 4; ++eti) {
        #pragma unroll
        for (int j = 0; j < 8; ++j) {
            fr[eti][0][j] = (__bf16)fmaxf((float)a0[eti][j] + (float)q0[eti][j], 0.f);
            fr[eti][1][j] = (__bf16)fmaxf((float)a1[eti][j] + (float)q1[eti][j], 0.f);
        }
    }

    // ---------------- GEMM2: H2^T = W2^T @ H1^T (4 tiles share each weight frag) ----------------
    f32x4 acc2[4][4];
    #pragma unroll
    for (int eti = 0; eti < 4; ++eti)
        #pragma unroll
        for (int ot = 0; ot < 4; ++ot)
            acc2[eti][ot] = (f32x4){0.f, 0.f, 0.f, 0.f};

    #pragma unroll
    for (int kt = 0; kt < 2; ++kt) {
        #pragma unroll
        for (int ot = 0; ot < 4; ++ot) {
            bf16x8 wf = w2v[(ot * 16 + ln) * 8 + kt * 4 + rg];
            #pragma unroll
            for (int eti = 0; eti < 4; ++eti)
                acc2[eti][ot] = __builtin_amdgcn_mfma_f32_16x16x32_bf16(
                    wf, fr[eti][kt], acc2[eti][ot], 0, 0, 0);
        }
    }

    // ---------------- epilogue: bias+relu -> bf16 h2 -> sB (wave-local rows) ----------------
    #pragma unroll
    for (int eti = 0; eti < 4; ++eti) {
        const int e = (w * 4 + eti) * 16 + ln;
        unsigned char* rowp = sB + e * 128;
        const unsigned int swz = (unsigned int)(e & 7) << 4;
        #pragma unroll
        for (int ot = 0; ot < 4; ++ot) {
            const int c0 = ot * 16 + rg * 4;
            float4 bv = *(const float4*)(b2 + c0);
            bf16x4 hv;
            hv[0] = (__bf16)fmaxf(acc2[eti][ot][0] + bv.x, 0.f);
            hv[1] = (__bf16)fmaxf(acc2[eti][ot][1] + bv.y, 0.f);
            hv[2] = (__bf16)fmaxf(acc2[eti][ot][2] + bv.z, 0.f);
            hv[3] = (__bf16)fmaxf(acc2[eti][ot][3] + bv.w, 0.f);
            *(bf16x4*)(rowp + (((unsigned)(c0 * 2)) ^ swz)) = hv;
        }
    }

    __syncthreads();

    // ---------------- segmented max over dst groups (4-wave strided) ----------------
    {
        const int dfirst = csr[p0].y;
        const int dlast  = csr[p1 - 1].y;
        const int c = lane;
        for (int d = dfirst + w; d <= dlast; d += 4) {
            const int s0 = starts[d], s1 = starts[d + 1];
            const int lo = max(s0, p0), hi = min(s1, p1);
            if (lo >= hi) continue;  // zero-edge node inside range
            unsigned int m0 = 0, m1 = 0;  // bf16 bits; relu>=0 so bit-max == fp-max
            int p = lo;
            for (; p + 1 < hi; p += 2) {
                const int e0 = p - p0, e1 = e0 + 1;
                unsigned int v0 = *(const unsigned short*)(sB + e0 * 128 +
                                    (((unsigned)(c * 2)) ^ ((unsigned)(e0 & 7) << 4)));
                unsigned int v1 = *(const unsigned short*)(sB + e1 * 128 +
                                    (((unsigned)(c * 2)) ^ ((unsigned)(e1 & 7) << 4)));
                m0 = max(m0, v0);
                m1 = max(m1, v1);
            }
            if (p < hi) {
                const int e0 = p - p0;
                unsigned int v0 = *(const unsigned short*)(sB + e0 * 128 +
                                    (((unsigned)(c * 2)) ^ ((unsigned)(e0 & 7) << 4)));
                m0 = max(m0, v0);
            }
            float m = __uint_as_float(max(m0, m1) << 16);
            if (s0 >= p0 && s1 <= p1)
                out[(long)d * 64 + c] = m;                                   // sole owner
            else
                atomicMax((int*)out + (long)d * 64 + c, __float_as_int(m));  // boundary
        }
    }
}

extern "C" void kernel_launch(void* const* d_in, const int* in_sizes, int n_in,
                              void* d_out, int out_size, void* d_ws, size_t ws_size,
                              hipStream_t stream) {
    const float* x  = (const float*)d_in[0];
    const int*   ei = (const int*)d_in[1];
    const float* W1 = (const float*)d_in[2];
    const float* b1 = (const float*)d_in[3];
    const float* W2 = (const float*)d_in[4];
    const float* b2 = (const float*)d_in[5];
    float* out = (float*)d_out;

    const int E = in_sizes[1] / 2;
    const int N = in_sizes[0] / 64;

    int* wsI = (int*)d_ws;
    int* counts  = wsI + OFF_COUNTS;
    int* starts  = wsI + OFF_STARTS;
    int* bsum    = wsI + OFF_BSUM;
    int2* csr    = (int2*)(wsI + OFF_CSR);
    unsigned short* wab = (unsigned short*)(wsI + OFF_CSR + 2 * E);
    unsigned short* Abf = (unsigned short*)(wsI + OFF_CSR + 2 * E + WAB_DW);
    unsigned short* Bbf = Abf + (long)N * 64;
    int* slot = (int*)Abf;   // aliases AB region; dead before ab_kernel runs

    hipMemsetAsync(counts, 0, (size_t)N * sizeof(int), stream);

    // weights prep + histogram (fused)
    const int nbH = (E / 4 + 255) / 256 + 1;
    prep_hist_kernel<<<48 + nbH, 256, 0, stream>>>(W1, W2, wab, ei, counts, slot, E);

    const int nb2 = (N + NSCAN - 1) / NSCAN;
    scanA_kernel<<<nb2, 256, 0, stream>>>(counts, bsum, N);
    scanB_kernel<<<1, 64, 0, stream>>>(bsum, starts, nb2, N, E);
    scanC_kernel<<<nb2, 256, 0, stream>>>(counts, bsum, starts, out, N);

    const int nbS = (E / 4 + 255) / 256 + 1;
    scatter_kernel<<<nbS, 256, 0, stream>>>(ei, starts, slot, csr, E);

    // now slot is dead -> ab_kernel may overwrite the region
    const int nbAB = (N + 63) / 64;
    ab_kernel<<<nbAB, 256, 0, stream>>>(x, wab, b1, Abf, Bbf, N);

    const int nb = (E + EB - 1) / EB;
    edgeconv_kernel<<<nb, 256, 0, stream>>>(Abf, Bbf, csr, starts, b2, wab, out, E);
}

// Round 15
// 228.568 us; speedup vs baseline: 1.2628x; 1.1209x over previous
//
#include <hip/hip_runtime.h>
#include <hip/hip_bf16.h>

typedef __bf16 bf16x8 __attribute__((ext_vector_type(8)));
typedef __bf16 bf16x4 __attribute__((ext_vector_type(4)));
typedef float f32x4 __attribute__((ext_vector_type(4)));

#define EB 128    // edges per block (edgeconv: 2 waves x 4 tiles x 16)
#define NSCAN 1024

// ---- ws layout (dword offsets) ----
#define OFF_COUNTS 0          // N dwords
#define OFF_STARTS 100000     // N+1 dwords
#define OFF_BSUM   200016     // ~128 dwords
#define OFF_CSR    200160     // int2[E] = 2E dwords
// wab (bf16[12288]: wA|wB|w2t) at OFF_CSR + 2E     [6144 dwords]
// AB region                     at OFF_CSR+2E+6144 [N*64 dwords]:
//   slot (int[E])  ALIASES the AB region (dead before ab_kernel writes A/B)
//   Abf (bf16[N*64]), Bbf (bf16[N*64]) written by ab_kernel AFTER scatter
#define WAB_DW 6144

__device__ __forceinline__ unsigned short f2bf(float v) {
    unsigned int u = __float_as_uint(v);
    return (unsigned short)((u + 0x7fffu + ((u >> 16) & 1u)) >> 16);
}

__device__ __forceinline__ bf16x8 pack8(float4 a, float4 b) {
    bf16x8 r;
    r[0] = (__bf16)a.x; r[1] = (__bf16)a.y; r[2] = (__bf16)a.z; r[3] = (__bf16)a.w;
    r[4] = (__bf16)b.x; r[5] = (__bf16)b.y; r[6] = (__bf16)b.z; r[7] = (__bf16)b.w;
    return r;
}

// blocks [0,48): weight prep (wA = W1a - W1b, wB = W1b, w2t = W2^T)
// blocks [48,..): histogram; atomicAdd return value IS the edge's slot
__global__ void prep_hist_kernel(const float* __restrict__ W1,
                                 const float* __restrict__ W2,
                                 unsigned short* __restrict__ wab,
                                 const int* __restrict__ ei,
                                 int* __restrict__ counts,
                                 int* __restrict__ slot, int E) {
    int b = blockIdx.x;
    if (b < 48) {
        int t = b * 256 + threadIdx.x;
        if (t < 4096) {
            int c = t >> 6, k = t & 63;
            wab[t] = f2bf(W1[k * 64 + c] - W1[(64 + k) * 64 + c]);
        } else if (t < 8192) {
            int i = t - 4096;
            int c = i >> 6, k = i & 63;
            wab[t] = f2bf(W1[(64 + k) * 64 + c]);
        } else if (t < 12288) {
            int i = t - 8192;
            int o = i >> 6, c = i & 63;
            wab[t] = f2bf(W2[c * 64 + o]);
        }
        return;
    }
    int t = (b - 48) * 256 + threadIdx.x;
    int i = t * 4;
    if (i + 3 < E) {
        int4 d = *(const int4*)(ei + E + i);
        int4 s;
        s.x = atomicAdd(&counts[d.x], 1);
        s.y = atomicAdd(&counts[d.y], 1);
        s.z = atomicAdd(&counts[d.z], 1);
        s.w = atomicAdd(&counts[d.w], 1);
        *(int4*)(slot + i) = s;
    } else {
        for (int j = 0; j < 4 && i + j < E; ++j)
            slot[i + j] = atomicAdd(&counts[ei[E + i + j]], 1);
    }
}

__global__ void scanA_kernel(const int* __restrict__ counts, int* __restrict__ bsum, int N) {
    int b = blockIdx.x, t = threadIdx.x;
    int base = b * NSCAN + t * 4;
    int s = 0;
    #pragma unroll
    for (int q = 0; q < 4; ++q)
        if (base + q < N) s += counts[base + q];
    #pragma unroll
    for (int off = 1; off < 64; off <<= 1) s += __shfl_xor(s, off);
    __shared__ int wsum[4];
    if ((t & 63) == 0) wsum[t >> 6] = s;
    __syncthreads();
    if (t == 0) bsum[b] = wsum[0] + wsum[1] + wsum[2] + wsum[3];
}

// single wave; nb <= 128
__global__ void scanB_kernel(int* __restrict__ bsum, int* __restrict__ starts, int nb, int N, int E) {
    int lane = threadIdx.x;
    int v0 = (lane < nb) ? bsum[lane] : 0;
    int v1 = (64 + lane < nb) ? bsum[64 + lane] : 0;
    int s = v0;
    #pragma unroll
    for (int off = 1; off < 64; off <<= 1) {
        int n = __shfl_up(s, off);
        if (lane >= off) s += n;
    }
    int total0 = __shfl(s, 63);
    int s1 = v1;
    #pragma unroll
    for (int off = 1; off < 64; off <<= 1) {
        int n = __shfl_up(s1, off);
        if (lane >= off) s1 += n;
    }
    if (lane < nb) bsum[lane] = s - v0;
    if (64 + lane < nb) bsum[64 + lane] = total0 + s1 - v1;
    if (lane == 0) starts[N] = E;
}

// writes starts[]; zero-fills out rows for zero-degree nodes (no global memset)
__global__ void scanC_kernel(const int* __restrict__ counts, const int* __restrict__ bsum,
                             int* __restrict__ starts, float* __restrict__ out, int N) {
    int b = blockIdx.x, t = threadIdx.x;
    int lane = t & 63, w = t >> 6;
    int base = b * NSCAN + t * 4;
    int c[4];
    #pragma unroll
    for (int q = 0; q < 4; ++q)
        c[q] = (base + q < N) ? counts[base + q] : 0;
    int tot = c[0] + c[1] + c[2] + c[3];
    int inc = tot;
    #pragma unroll
    for (int off = 1; off < 64; off <<= 1) {
        int n = __shfl_up(inc, off);
        if (lane >= off) inc += n;
    }
    int excl = inc - tot;
    __shared__ int wtot[4];
    if (lane == 63) wtot[w] = inc;
    __syncthreads();
    int woff = 0;
    for (int i = 0; i < w; ++i) woff += wtot[i];
    int run = bsum[b] + woff + excl;
    #pragma unroll
    for (int q = 0; q < 4; ++q) {
        if (base + q < N) {
            starts[base + q] = run;
            if (c[q] == 0) {   // ~never (E = 16N random), but must be exact
                f32x4 z = (f32x4){0.f, 0.f, 0.f, 0.f};
                float* op = out + (long)(base + q) * 64;
                #pragma unroll
                for (int r = 0; r < 16; ++r) *(f32x4*)(op + r * 4) = z;
            }
            run += c[q];
        }
    }
}

// atomic-free scatter using precomputed slots (4 edges/thread)
__global__ void scatter_kernel(const int* __restrict__ ei, const int* __restrict__ starts,
                               const int* __restrict__ slot, int2* __restrict__ csr, int E) {
    int t = blockIdx.x * blockDim.x + threadIdx.x;
    int i = t * 4;
    if (i + 3 < E) {
        int4 s4 = *(const int4*)(ei + i);
        int4 d4 = *(const int4*)(ei + E + i);
        int4 sl = *(const int4*)(slot + i);
        csr[starts[d4.x] + sl.x] = make_int2(s4.x, d4.x);
        csr[starts[d4.y] + sl.y] = make_int2(s4.y, d4.y);
        csr[starts[d4.z] + sl.z] = make_int2(s4.z, d4.z);
        csr[starts[d4.w] + sl.w] = make_int2(s4.w, d4.w);
    } else {
        for (int j = 0; j < 4 && i + j < E; ++j) {
            int sE = ei[i + j], dE = ei[E + i + j];
            csr[starts[dE] + slot[i + j]] = make_int2(sE, dE);
        }
    }
}

// A = x @ wA^T + b1, B = x @ wB^T   (per node; bf16 out, f32 accum)
__global__ __launch_bounds__(256, 4)
void ab_kernel(const float* __restrict__ x,
               const unsigned short* __restrict__ wab,
               const float* __restrict__ b1,
               unsigned short* __restrict__ Abf,
               unsigned short* __restrict__ Bbf, int N) {
    const int lane = threadIdx.x & 63;
    const int w    = threadIdx.x >> 6;
    const int ln   = lane & 15;
    const int rg   = lane >> 4;
    const int n    = blockIdx.x * 64 + w * 16 + ln;
    const int nc   = min(n, N - 1);

    const float* xr = x + (long)nc * 64;
    float4 f0 = *(const float4*)(xr + rg * 8),      f1 = *(const float4*)(xr + rg * 8 + 4);
    float4 f2 = *(const float4*)(xr + 32 + rg * 8), f3 = *(const float4*)(xr + 32 + rg * 8 + 4);
    bf16x8 xk[2];
    xk[0] = pack8(f0, f1);
    xk[1] = pack8(f2, f3);

    const bf16x8* wAv = (const bf16x8*)wab;            // 64 rows x 8 frags
    const bf16x8* wBv = (const bf16x8*)(wab + 4096);

    f32x4 accA[4], accB[4];
    #pragma unroll
    for (int ct = 0; ct < 4; ++ct) {
        accA[ct] = (f32x4){0.f, 0.f, 0.f, 0.f};
        accB[ct] = (f32x4){0.f, 0.f, 0.f, 0.f};
    }
    #pragma unroll
    for (int kt = 0; kt < 2; ++kt) {
        #pragma unroll
        for (int ct = 0; ct < 4; ++ct) {
            accA[ct] = __builtin_amdgcn_mfma_f32_16x16x32_bf16(
                wAv[(ct * 16 + ln) * 8 + kt * 4 + rg], xk[kt], accA[ct], 0, 0, 0);
            accB[ct] = __builtin_amdgcn_mfma_f32_16x16x32_bf16(
                wBv[(ct * 16 + ln) * 8 + kt * 4 + rg], xk[kt], accB[ct], 0, 0, 0);
        }
    }
    if (n < N) {
        #pragma unroll
        for (int ct = 0; ct < 4; ++ct) {
            const int c0 = ct * 16 + rg * 4;
            float4 bv = *(const float4*)(b1 + c0);
            bf16x4 av, bvv;
            av[0] = (__bf16)(accA[ct][0] + bv.x);
            av[1] = (__bf16)(accA[ct][1] + bv.y);
            av[2] = (__bf16)(accA[ct][2] + bv.z);
            av[3] = (__bf16)(accA[ct][3] + bv.w);
            bvv[0] = (__bf16)accB[ct][0];
            bvv[1] = (__bf16)accB[ct][1];
            bvv[2] = (__bf16)accB[ct][2];
            bvv[3] = (__bf16)accB[ct][3];
            *(bf16x4*)(Abf + (long)n * 64 + c0) = av;
            *(bf16x4*)(Bbf + (long)n * 64 + c0) = bvv;
        }
    }
}

__global__ __launch_bounds__(128)
void edgeconv_kernel(const unsigned short* __restrict__ Abf,
                     const unsigned short* __restrict__ Bbf,
                     const int2* __restrict__ csr,
                     const int* __restrict__ starts,
                     const float* __restrict__ b2,
                     const unsigned short* __restrict__ wab,
                     float* __restrict__ out,
                     int E) {
    // sB (16KB): h2 bf16 [128][64], rows 128B, XOR swizzle (e&7)<<4 on 16B chunks.
    __shared__ __align__(16) unsigned char sB[EB * 128];

    const int tid  = threadIdx.x;         // 0..127 (2 waves)
    const int lane = tid & 63;
    const int w    = tid >> 6;            // wave 0..1
    const int ln   = lane & 15;
    const int rg   = lane >> 4;           // 0..3
    const int p0   = blockIdx.x * EB;
    const int p1   = min(p0 + EB, E);

    const bf16x8* w2v = (const bf16x8*)(wab + 8192);

    // ---------------- gather + add + relu: 4 edge-tiles per wave ----------------
    // h1(e) = relu(A[dst] + B[src]); wave w owns edges e = (w*4+eti)*16 + ln.
    bf16x8 fr[4][2];
    #pragma unroll
    for (int eti = 0; eti < 4; ++eti) {
        const int p = p0 + (w * 4 + eti) * 16 + ln;
        int2 sd = (p < E) ? csr[p] : make_int2(0, 0);
        const unsigned short* Ai = Abf + (long)sd.y * 64;
        const unsigned short* Bj = Bbf + (long)sd.x * 64;
        bf16x8 a0 = *(const bf16x8*)(Ai + rg * 8);
        bf16x8 a1 = *(const bf16x8*)(Ai + 32 + rg * 8);
        bf16x8 q0 = *(const bf16x8*)(Bj + rg * 8);
        bf16x8 q1 = *(const bf16x8*)(Bj + 32 + rg * 8);
        #pragma unroll
        for (int j = 0; j < 8; ++j) {
            fr[eti][0][j] = (__bf16)fmaxf((float)a0[j] + (float)q0[j], 0.f);
            fr[eti][1][j] = (__bf16)fmaxf((float)a1[j] + (float)q1[j], 0.f);
        }
    }

    // ---------------- GEMM2: H2^T = W2^T @ H1^T (4 tiles share each weight frag) ----------------
    f32x4 acc2[4][4];
    #pragma unroll
    for (int eti = 0; eti < 4; ++eti)
        #pragma unroll
        for (int ot = 0; ot < 4; ++ot)
            acc2[eti][ot] = (f32x4){0.f, 0.f, 0.f, 0.f};

    #pragma unroll
    for (int kt = 0; kt < 2; ++kt) {
        #pragma unroll
        for (int ot = 0; ot < 4; ++ot) {
            bf16x8 wf = w2v[(ot * 16 + ln) * 8 + kt * 4 + rg];
            #pragma unroll
            for (int eti = 0; eti < 4; ++eti)
                acc2[eti][ot] = __builtin_amdgcn_mfma_f32_16x16x32_bf16(
                    wf, fr[eti][kt], acc2[eti][ot], 0, 0, 0);
        }
    }

    // ---------------- epilogue: bias+relu -> bf16 h2 -> sB (wave-local rows) ----------------
    #pragma unroll
    for (int eti = 0; eti < 4; ++eti) {
        const int e = (w * 4 + eti) * 16 + ln;
        unsigned char* rowp = sB + e * 128;
        const unsigned int swz = (unsigned int)(e & 7) << 4;
        #pragma unroll
        for (int ot = 0; ot < 4; ++ot) {
            const int c0 = ot * 16 + rg * 4;
            float4 bv = *(const float4*)(b2 + c0);
            bf16x4 hv;
            hv[0] = (__bf16)fmaxf(acc2[eti][ot][0] + bv.x, 0.f);
            hv[1] = (__bf16)fmaxf(acc2[eti][ot][1] + bv.y, 0.f);
            hv[2] = (__bf16)fmaxf(acc2[eti][ot][2] + bv.z, 0.f);
            hv[3] = (__bf16)fmaxf(acc2[eti][ot][3] + bv.w, 0.f);
            *(bf16x4*)(rowp + (((unsigned)(c0 * 2)) ^ swz)) = hv;
        }
    }

    __syncthreads();   // 2-wave barrier

    // ---------------- segmented max over dst groups (2-wave strided) ----------------
    {
        const int dfirst = csr[p0].y;
        const int dlast  = csr[p1 - 1].y;
        const int c = lane;
        for (int d = dfirst + w; d <= dlast; d += 2) {
            const int s0 = starts[d], s1 = starts[d + 1];
            const int lo = max(s0, p0), hi = min(s1, p1);
            if (lo >= hi) continue;  // zero-edge node inside range
            unsigned int m0 = 0, m1 = 0;  // bf16 bits; relu>=0 so bit-max == fp-max
            int p = lo;
            for (; p + 1 < hi; p += 2) {
                const int e0 = p - p0, e1 = e0 + 1;
                unsigned int v0 = *(const unsigned short*)(sB + e0 * 128 +
                                    (((unsigned)(c * 2)) ^ ((unsigned)(e0 & 7) << 4)));
                unsigned int v1 = *(const unsigned short*)(sB + e1 * 128 +
                                    (((unsigned)(c * 2)) ^ ((unsigned)(e1 & 7) << 4)));
                m0 = max(m0, v0);
                m1 = max(m1, v1);
            }
            if (p < hi) {
                const int e0 = p - p0;
                unsigned int v0 = *(const unsigned short*)(sB + e0 * 128 +
                                    (((unsigned)(c * 2)) ^ ((unsigned)(e0 & 7) << 4)));
                m0 = max(m0, v0);
            }
            float m = __uint_as_float(max(m0, m1) << 16);
            if (s0 >= p0 && s1 <= p1)
                out[(long)d * 64 + c] = m;                                   // sole owner
            else
                atomicMax((int*)out + (long)d * 64 + c, __float_as_int(m));  // boundary
        }
    }
}

extern "C" void kernel_launch(void* const* d_in, const int* in_sizes, int n_in,
                              void* d_out, int out_size, void* d_ws, size_t ws_size,
                              hipStream_t stream) {
    const float* x  = (const float*)d_in[0];
    const int*   ei = (const int*)d_in[1];
    const float* W1 = (const float*)d_in[2];
    const float* b1 = (const float*)d_in[3];
    const float* W2 = (const float*)d_in[4];
    const float* b2 = (const float*)d_in[5];
    float* out = (float*)d_out;

    const int E = in_sizes[1] / 2;
    const int N = in_sizes[0] / 64;

    int* wsI = (int*)d_ws;
    int* counts  = wsI + OFF_COUNTS;
    int* starts  = wsI + OFF_STARTS;
    int* bsum    = wsI + OFF_BSUM;
    int2* csr    = (int2*)(wsI + OFF_CSR);
    unsigned short* wab = (unsigned short*)(wsI + OFF_CSR + 2 * E);
    unsigned short* Abf = (unsigned short*)(wsI + OFF_CSR + 2 * E + WAB_DW);
    unsigned short* Bbf = Abf + (long)N * 64;
    int* slot = (int*)Abf;   // aliases AB region; dead before ab_kernel runs

    hipMemsetAsync(counts, 0, (size_t)N * sizeof(int), stream);

    // weights prep + histogram (fused)
    const int nbH = (E / 4 + 255) / 256 + 1;
    prep_hist_kernel<<<48 + nbH, 256, 0, stream>>>(W1, W2, wab, ei, counts, slot, E);

    const int nb2 = (N + NSCAN - 1) / NSCAN;
    scanA_kernel<<<nb2, 256, 0, stream>>>(counts, bsum, N);
    scanB_kernel<<<1, 64, 0, stream>>>(bsum, starts, nb2, N, E);
    scanC_kernel<<<nb2, 256, 0, stream>>>(counts, bsum, starts, out, N);

    const int nbS = (E / 4 + 255) / 256 + 1;
    scatter_kernel<<<nbS, 256, 0, stream>>>(ei, starts, slot, csr, E);

    // now slot is dead -> ab_kernel may overwrite the region
    const int nbAB = (N + 63) / 64;
    ab_kernel<<<nbAB, 256, 0, stream>>>(x, wab, b1, Abf, Bbf, N);

    const int nb = (E + EB - 1) / EB;
    edgeconv_kernel<<<nb, 128, 0, stream>>>(Abf, Bbf, csr, starts, b2, wab, out, E);
}